// Round 5
// baseline (273.242 us; speedup 1.0000x reference)
//
#include <hip/hip_runtime.h>
#include <hip/hip_bf16.h>

typedef unsigned short ushort_t;
typedef __bf16 bf16x8 __attribute__((ext_vector_type(8)));
typedef unsigned short us8 __attribute__((ext_vector_type(8)));
typedef float f32x4 __attribute__((ext_vector_type(4)));

__device__ __forceinline__ float b2f(ushort_t h) {
    union { unsigned int u; float f; } v; v.u = ((unsigned int)h) << 16; return v.f;
}
__device__ __forceinline__ ushort_t f2b(float f) {
    union { float f; unsigned int u; } v; v.f = f;
    unsigned int u = v.u;
    unsigned int r = (u + 0x7FFFu + ((u >> 16) & 1u)) >> 16;
    return (ushort_t)r;
}
__device__ __forceinline__ float sigmoidf_(float x) {
    return 1.f / (1.f + __expf(-x));
}
__device__ __forceinline__ void store_o(ushort_t* p, float v) { *p = f2b(v); }
__device__ __forceinline__ void store_o(float* p, float v) { *p = v; }

// ---------------------------------------------------------------------------
__global__ void fill_kernel(float* out, long long n, float val) {
    long long i = (long long)blockIdx.x * blockDim.x + threadIdx.x;
    if (i < n) out[i] = val;
}

// fp32 -> bf16 canonicalize (count divisible by 8)
__global__ void canon_kernel(const float* __restrict__ src,
                             ushort_t* __restrict__ dst, long long n8) {
    long long i = (long long)blockIdx.x * blockDim.x + threadIdx.x;
    if (i >= n8) return;
    long long base = i * 8;
    us8 o;
    #pragma unroll
    for (int k = 0; k < 8; k++) o[k] = f2b(src[base + k]);
    *(us8*)(dst + base) = o;
}

// ---------------------------------------------------------------------------
// Bucket sort rows by agent id. Single block. perm[pos] = original row.
// ---------------------------------------------------------------------------
__global__ void sort_kernel(const int* __restrict__ ids, int N,
                            int* __restrict__ perm, int* __restrict__ seg) {
    __shared__ int cnt[8];
    __shared__ int off[8];
    int tid = threadIdx.x;
    if (tid < 8) cnt[tid] = 0;
    __syncthreads();
    for (int n = tid; n < N; n += blockDim.x) atomicAdd(&cnt[ids[n] & 7], 1);
    __syncthreads();
    if (tid == 0) {
        int s = 0;
        for (int a = 0; a < 8; a++) { off[a] = s; seg[a] = s; s += cnt[a]; }
        seg[8] = s;
    }
    __syncthreads();
    for (int n = tid; n < N; n += blockDim.x) {
        int p = atomicAdd(&off[ids[n] & 7], 1);
        perm[p] = n;
    }
}

// ---------------------------------------------------------------------------
// Masked weights (fp32 in, bf16 out)
// ---------------------------------------------------------------------------
__global__ void maskw_kernel(const float* __restrict__ alpha,
                             const float* __restrict__ w,
                             ushort_t* __restrict__ wm,
                             int A, int O, int G) {
    long long idx = (long long)blockIdx.x * blockDim.x + threadIdx.x;
    long long total = (long long)A * O * G;
    if (idx >= total) return;
    int g = (int)(idx % G);
    long long t2 = idx / G;
    int o = (int)(t2 % O);
    const float* al = alpha + idx * 6;
    float p[6];
    float mx = -1e30f;
    #pragma unroll
    for (int i = 0; i < 6; i++) { p[i] = al[i] * 0.2f; mx = fmaxf(mx, p[i]); }
    float s = 0.f;
    #pragma unroll
    for (int i = 0; i < 6; i++) { p[i] = __expf(p[i] - mx); s += p[i]; }
    float inv = 1.f / s;
    #pragma unroll
    for (int i = 0; i < 6; i++) p[i] *= inv;
    float mk[4] = { p[0] + p[1] + p[2], p[0] + p[3] + p[4],
                    p[1] + p[3] + p[5], p[2] + p[4] + p[5] };
    int K = G * 4;
    const float* wr = w + (long long)o * K + g * 4;
    ushort_t* wo = wm + (idx / G) * (long long)K + g * 4;
    #pragma unroll
    for (int k = 0; k < 4; k++) wo[k] = f2b(wr[k] * mk[k]);
}

// ---------------------------------------------------------------------------
// Segmented MFMA GEMM, output type templated (bf16 internal / fp32 final)
// ---------------------------------------------------------------------------
#define BM 64
#define BN 64
#define BK 32
#define LDT 40  // LDS row stride: 80B -> 16B aligned, 2-way banks (free, m136)

template <typename OT>
__launch_bounds__(256, 4)
__global__ void gemm_seg(const ushort_t* __restrict__ In, int ldin,
                         const ushort_t* __restrict__ W, long long w_seg_stride,
                         const float* __restrict__ bias,
                         OT* __restrict__ Out, int ldo,
                         const int* __restrict__ seg,
                         const int* __restrict__ gather,
                         const int* __restrict__ scatter,
                         int O, int K, int relu) {
    int a = blockIdx.z;
    int seg0 = seg[a], seg1 = seg[a + 1];
    int m0 = blockIdx.x * BM;
    if (seg0 + m0 >= seg1) return;
    int o0 = blockIdx.y * BN;
    if (o0 >= O) return;

    __shared__ ushort_t As[BM * LDT];
    __shared__ ushort_t Bs[BN * LDT];

    int tid = threadIdx.x;
    int wave = tid >> 6, lane = tid & 63;
    int wr = (wave >> 1) & 1, wc = wave & 1;
    int quad = lane >> 4, l16 = lane & 15;

    int srow = tid >> 2;
    int scol = (tid & 3) * 8;

    int apos = seg0 + m0 + srow;
    int apos_c = apos < seg1 ? apos : (seg1 - 1);
    int arow = (gather ? gather[apos_c] : apos_c) & 8191;
    const ushort_t* aptr = In + (long long)arow * ldin + scol;

    int brow = o0 + srow;
    int brow_c = brow < O ? brow : (O - 1);
    const ushort_t* bptr = W + (long long)a * w_seg_stride + (long long)brow_c * K + scol;

    f32x4 acc[2][2];
    #pragma unroll
    for (int i = 0; i < 2; i++)
        #pragma unroll
        for (int j = 0; j < 2; j++) acc[i][j] = (f32x4){0.f, 0.f, 0.f, 0.f};

    for (int k0 = 0; k0 < K; k0 += BK) {
        us8 av = *(const us8*)(aptr + k0);
        us8 bv = *(const us8*)(bptr + k0);
        __syncthreads();
        *(us8*)(&As[srow * LDT + scol]) = av;
        *(us8*)(&Bs[srow * LDT + scol]) = bv;
        __syncthreads();

        bf16x8 af[2], bfr[2];
        #pragma unroll
        for (int t = 0; t < 2; t++) {
            af[t]  = *(const bf16x8*)(&As[(wr * 32 + t * 16 + l16) * LDT + quad * 8]);
            bfr[t] = *(const bf16x8*)(&Bs[(wc * 32 + t * 16 + l16) * LDT + quad * 8]);
        }
        #pragma unroll
        for (int i = 0; i < 2; i++)
            #pragma unroll
            for (int j = 0; j < 2; j++)
                acc[i][j] = __builtin_amdgcn_mfma_f32_16x16x32_bf16(af[i], bfr[j], acc[i][j], 0, 0, 0);
    }

    #pragma unroll
    for (int i = 0; i < 2; i++) {
        int mbase = m0 + wr * 32 + i * 16 + quad * 4;
        #pragma unroll
        for (int j = 0; j < 2; j++) {
            int col = o0 + wc * 32 + j * 16 + l16;
            if (col < O) {
                float bias_v = bias ? bias[col] : 0.f;
                #pragma unroll
                for (int r = 0; r < 4; r++) {
                    int pos = seg0 + mbase + r;
                    if (pos < seg1) {
                        float v = acc[i][j][r] + bias_v;
                        if (relu) v = fmaxf(v, 0.f);
                        int orow = (scatter ? scatter[pos] : pos) & 8191;
                        store_o(&Out[(long long)orow * ldo + col], v);
                    }
                }
            }
        }
    }
}

// ---------------------------------------------------------------------------
// Fused GRU: GI = y1@wih^T, GH = h@whh^T + gate math in one kernel.
// Writes h' fp32 to out_h_f (d_out, ORIGINAL row order) and bf16 to hp
// (ws, POS order, feeds fc2 with no gather).
// ---------------------------------------------------------------------------
__launch_bounds__(256, 2)
__global__ void gru_fused(const ushort_t* __restrict__ y1,       // [N,H] pos order bf16
                          const ushort_t* __restrict__ hid_b,    // [N,H] orig order bf16
                          const float* __restrict__ hidden_f,    // [N,H] orig order fp32
                          const ushort_t* __restrict__ wihb,     // [3H,H] bf16
                          const ushort_t* __restrict__ whhb,     // [3H,H] bf16
                          const float* __restrict__ bih,         // [3H] fp32
                          const float* __restrict__ bhh,         // [3H] fp32
                          const int* __restrict__ perm,
                          float* __restrict__ out_h_f,           // [N,H] orig order fp32
                          ushort_t* __restrict__ hp,             // [N,H] pos order bf16
                          int N, int H) {
    int m0 = blockIdx.x * 64;
    int c0 = blockIdx.y * 64;

    __shared__ ushort_t Ay[64 * LDT];
    __shared__ ushort_t Ah[64 * LDT];
    __shared__ ushort_t Bt[6][64 * LDT];

    int tid = threadIdx.x;
    int wave = tid >> 6, lane = tid & 63;
    int wr = (wave >> 1) & 1, wc = wave & 1;
    int quad = lane >> 4, l16 = lane & 15;
    int srow = tid >> 2;
    int scol = (tid & 3) * 8;

    int hrow = perm[m0 + srow] & 8191;
    const ushort_t* ay_p = y1 + (long long)(m0 + srow) * H + scol;
    const ushort_t* ah_p = hid_b + (long long)hrow * H + scol;
    const ushort_t* bp[6];
    #pragma unroll
    for (int g = 0; g < 3; g++)
        bp[g] = wihb + (long long)(g * H + c0 + srow) * H + scol;
    #pragma unroll
    for (int g = 3; g < 6; g++)
        bp[g] = whhb + (long long)((g - 3) * H + c0 + srow) * H + scol;

    f32x4 acc[6][2][2];
    #pragma unroll
    for (int g = 0; g < 6; g++)
        #pragma unroll
        for (int i = 0; i < 2; i++)
            #pragma unroll
            for (int j = 0; j < 2; j++) acc[g][i][j] = (f32x4){0.f, 0.f, 0.f, 0.f};

    for (int k0 = 0; k0 < H; k0 += BK) {
        us8 va = *(const us8*)(ay_p + k0);
        us8 vh = *(const us8*)(ah_p + k0);
        us8 vb[6];
        #pragma unroll
        for (int g = 0; g < 6; g++) vb[g] = *(const us8*)(bp[g] + k0);
        __syncthreads();
        *(us8*)(&Ay[srow * LDT + scol]) = va;
        *(us8*)(&Ah[srow * LDT + scol]) = vh;
        #pragma unroll
        for (int g = 0; g < 6; g++) *(us8*)(&Bt[g][srow * LDT + scol]) = vb[g];
        __syncthreads();

        bf16x8 ayf[2], ahf[2];
        #pragma unroll
        for (int t = 0; t < 2; t++) {
            ayf[t] = *(const bf16x8*)(&Ay[(wr * 32 + t * 16 + l16) * LDT + quad * 8]);
            ahf[t] = *(const bf16x8*)(&Ah[(wr * 32 + t * 16 + l16) * LDT + quad * 8]);
        }
        #pragma unroll
        for (int g = 0; g < 6; g++) {
            bf16x8 bfr[2];
            #pragma unroll
            for (int t = 0; t < 2; t++)
                bfr[t] = *(const bf16x8*)(&Bt[g][(wc * 32 + t * 16 + l16) * LDT + quad * 8]);
            #pragma unroll
            for (int i = 0; i < 2; i++)
                #pragma unroll
                for (int j = 0; j < 2; j++)
                    acc[g][i][j] = __builtin_amdgcn_mfma_f32_16x16x32_bf16(
                        (g < 3) ? ayf[i] : ahf[i], bfr[j], acc[g][i][j], 0, 0, 0);
        }
    }

    #pragma unroll
    for (int i = 0; i < 2; i++) {
        #pragma unroll
        for (int r = 0; r < 4; r++) {
            int pos = m0 + wr * 32 + i * 16 + quad * 4 + r;
            int norig = perm[pos] & 8191;
            #pragma unroll
            for (int j = 0; j < 2; j++) {
                int col = c0 + wc * 32 + j * 16 + l16;
                float ir = acc[0][i][j][r] + bih[col];
                float iz = acc[1][i][j][r] + bih[H + col];
                float in_ = acc[2][i][j][r] + bih[2 * H + col];
                float hr = acc[3][i][j][r] + bhh[col];
                float hz = acc[4][i][j][r] + bhh[H + col];
                float hn = acc[5][i][j][r] + bhh[2 * H + col];
                float rg = sigmoidf_(ir + hr);
                float zg = sigmoidf_(iz + hz);
                float ng = tanhf(in_ + rg * hn);
                float hv = hidden_f[(long long)norig * H + col];
                float hnew = (1.f - zg) * ng + zg * hv;
                out_h_f[(long long)norig * H + col] = hnew;
                hp[(long long)pos * H + col] = f2b(hnew);
            }
        }
    }
}

// ---------------------------------------------------------------------------
extern "C" void kernel_launch(void* const* d_in, const int* in_sizes, int n_in,
                              void* d_out, int out_size, void* d_ws, size_t ws_size,
                              hipStream_t stream) {
    (void)in_sizes; (void)n_in;
    const int N = 8192, A = 8, E = 64, H = 512, NA = 16;

    float* out_f = (float*)d_out;
    float* out_q = out_f;                        // [N, NA] fp32
    float* out_h = out_f + (size_t)N * NA;       // [N, H] fp32, original row order

    // Workspace (~38.5 MB)
    char* p = (char*)d_ws;
    auto alloc = [&](size_t b) { char* r = p; p += (b + 255) & ~(size_t)255; return r; };
    int* perm = (int*)alloc((size_t)N * 4);
    int* seg  = (int*)alloc(16 * 4);
    ushort_t* wm1  = (ushort_t*)alloc((size_t)A * H * E * 2);
    ushort_t* wm2  = (ushort_t*)alloc((size_t)A * H * H * 2);
    ushort_t* wm3  = (ushort_t*)alloc((size_t)A * H * H * 2);
    ushort_t* wm4  = (ushort_t*)alloc((size_t)A * NA * H * 2);
    ushort_t* y1   = (ushort_t*)alloc((size_t)N * H * 2);
    ushort_t* inp_b = (ushort_t*)alloc((size_t)N * E * 2);
    ushort_t* hid_b = (ushort_t*)alloc((size_t)N * H * 2);
    ushort_t* wihb  = (ushort_t*)alloc((size_t)3 * H * H * 2);
    ushort_t* whhb  = (ushort_t*)alloc((size_t)3 * H * H * 2);
    ushort_t* hp    = (ushort_t*)alloc((size_t)N * H * 2);
    size_t need = (size_t)(p - (char*)d_ws);
    ushort_t* q2 = y1;     // alias: y1 dead after gru_fused
    ushort_t* q3 = hid_b;  // alias: hid_b dead after gru_fused

    if (ws_size < need) {   // diagnose: absmax ~1000 => ws too small
        fill_kernel<<<(unsigned)((out_size + 255) / 256), 256, 0, stream>>>(
            out_f, out_size, 1000.f);
        return;
    }

    const float* inputs = (const float*)d_in[0];
    const float* hidden = (const float*)d_in[1];
    const int*   ids    = (const int*)d_in[2];
    const float* fc1_w  = (const float*)d_in[3];
    const float* fc1_b  = (const float*)d_in[4];
    const float* fc1_al = (const float*)d_in[5];
    const float* wih    = (const float*)d_in[6];
    const float* whh    = (const float*)d_in[7];
    const float* bih    = (const float*)d_in[8];
    const float* bhh    = (const float*)d_in[9];
    const float* fc2_w  = (const float*)d_in[10];
    const float* fc2_b  = (const float*)d_in[11];
    const float* fc2_al = (const float*)d_in[12];
    const float* fc3_w  = (const float*)d_in[13];
    const float* fc3_b  = (const float*)d_in[14];
    const float* fc3_al = (const float*)d_in[15];
    const float* fc4_w  = (const float*)d_in[16];
    const float* fc4_b  = (const float*)d_in[17];
    const float* fc4_al = (const float*)d_in[18];

    sort_kernel<<<1, 1024, 0, stream>>>(ids, N, perm, seg);

    {
        long long n;
        n = (long long)N * E / 8;
        canon_kernel<<<(unsigned)((n + 255) / 256), 256, 0, stream>>>(inputs, inp_b, n);
        n = (long long)N * H / 8;
        canon_kernel<<<(unsigned)((n + 255) / 256), 256, 0, stream>>>(hidden, hid_b, n);
        n = (long long)3 * H * H / 8;
        canon_kernel<<<(unsigned)((n + 255) / 256), 256, 0, stream>>>(wih, wihb, n);
        canon_kernel<<<(unsigned)((n + 255) / 256), 256, 0, stream>>>(whh, whhb, n);
    }
    {
        long long t1 = (long long)A * H * (E / 4);
        maskw_kernel<<<(unsigned)((t1 + 255) / 256), 256, 0, stream>>>(fc1_al, fc1_w, wm1, A, H, E / 4);
        long long t2 = (long long)A * H * (H / 4);
        maskw_kernel<<<(unsigned)((t2 + 255) / 256), 256, 0, stream>>>(fc2_al, fc2_w, wm2, A, H, H / 4);
        maskw_kernel<<<(unsigned)((t2 + 255) / 256), 256, 0, stream>>>(fc3_al, fc3_w, wm3, A, H, H / 4);
        long long t4 = (long long)A * NA * (H / 4);
        maskw_kernel<<<(unsigned)((t4 + 255) / 256), 256, 0, stream>>>(fc4_al, fc4_w, wm4, A, NA, H / 4);
    }

    dim3 blk(256);
    // fc1: per-agent, gather inputs via perm, relu -> y1 (pos order, bf16)
    gemm_seg<ushort_t><<<dim3(N / BM, H / BN, A), blk, 0, stream>>>(
        inp_b, E, wm1, (long long)H * E, fc1_b, y1, H, seg, perm, nullptr, H, E, 1);
    // fused GRU -> h' fp32 to d_out (orig order) + bf16 hp (pos order)
    gru_fused<<<dim3(N / 64, H / 64, 1), blk, 0, stream>>>(
        y1, hid_b, hidden, wihb, whhb, bih, bhh, perm, out_h, hp, N, H);
    // fc2: pos-order input (no gather), relu -> q2
    gemm_seg<ushort_t><<<dim3(N / BM, H / BN, A), blk, 0, stream>>>(
        hp, H, wm2, (long long)H * H, fc2_b, q2, H, seg, nullptr, nullptr, H, H, 1);
    // fc3: relu -> q3
    gemm_seg<ushort_t><<<dim3(N / BM, H / BN, A), blk, 0, stream>>>(
        q2, H, wm3, (long long)H * H, fc3_b, q3, H, seg, nullptr, nullptr, H, H, 1);
    // fc4: scatter q fp32 to d_out (orig order)
    gemm_seg<float><<<dim3(N / BM, 1, A), blk, 0, stream>>>(
        q3, H, wm4, (long long)NA * H, fc4_b, out_q, NA, seg, nullptr, perm, NA, H, 0);
}

// Round 6
// 244.841 us; speedup vs baseline: 1.1160x; 1.1160x over previous
//
#include <hip/hip_runtime.h>
#include <hip/hip_bf16.h>

typedef unsigned short ushort_t;
typedef __bf16 bf16x8 __attribute__((ext_vector_type(8)));
typedef unsigned short us8 __attribute__((ext_vector_type(8)));
typedef float f32x4 __attribute__((ext_vector_type(4)));

__device__ __forceinline__ float b2f(ushort_t h) {
    union { unsigned int u; float f; } v; v.u = ((unsigned int)h) << 16; return v.f;
}
__device__ __forceinline__ ushort_t f2b(float f) {
    union { float f; unsigned int u; } v; v.f = f;
    unsigned int u = v.u;
    unsigned int r = (u + 0x7FFFu + ((u >> 16) & 1u)) >> 16;
    return (ushort_t)r;
}
__device__ __forceinline__ float sigmoidf_(float x) {
    return 1.f / (1.f + __expf(-x));
}
__device__ __forceinline__ void store_o(ushort_t* p, float v) { *p = f2b(v); }
__device__ __forceinline__ void store_o(float* p, float v) { *p = v; }

__global__ void fill_kernel(float* out, long long n, float val) {
    long long i = (long long)blockIdx.x * blockDim.x + threadIdx.x;
    if (i < n) out[i] = val;
}

// ---------------------------------------------------------------------------
// Sort rows by agent id (1 block) + emit BM=64 tile table for segmented GEMMs.
// ---------------------------------------------------------------------------
__global__ void sort_kernel(const int* __restrict__ ids, int N,
                            int* __restrict__ perm, int* __restrict__ seg,
                            int4* __restrict__ ttab, int* __restrict__ tcount) {
    __shared__ int cnt[8];
    __shared__ int off[8];
    int tid = threadIdx.x;
    if (tid < 8) cnt[tid] = 0;
    __syncthreads();
    for (int n = tid; n < N; n += blockDim.x) atomicAdd(&cnt[ids[n] & 7], 1);
    __syncthreads();
    if (tid == 0) {
        int s = 0;
        for (int a = 0; a < 8; a++) { off[a] = s; seg[a] = s; s += cnt[a]; }
        seg[8] = s;
        int T = 0;
        for (int a = 0; a < 8; a++)
            for (int m = seg[a]; m < seg[a + 1]; m += 64) {
                int e = seg[a + 1] < m + 64 ? seg[a + 1] : m + 64;
                ttab[T++] = make_int4(a, m, e, 0);
            }
        *tcount = T;
    }
    __syncthreads();
    for (int n = tid; n < N; n += blockDim.x) {
        int p = atomicAdd(&off[ids[n] & 7], 1);
        perm[p] = n;
    }
}

// ---------------------------------------------------------------------------
// One fused prep kernel: 4x masked-weight build + 4x fp32->bf16 canonicalize.
// Grid partitioned by blockIdx.x; every section's item count is a multiple
// of 256 so no bounds checks needed.
// ---------------------------------------------------------------------------
__device__ __forceinline__ void maskw_item(const float* __restrict__ alpha,
                                           const float* __restrict__ w,
                                           ushort_t* __restrict__ wm,
                                           long long idx, int O, int G) {
    int g = (int)(idx % G);
    long long t2 = idx / G;
    int o = (int)(t2 % O);
    const float* al = alpha + idx * 6;
    float p[6];
    float mx = -1e30f;
    #pragma unroll
    for (int i = 0; i < 6; i++) { p[i] = al[i] * 0.2f; mx = fmaxf(mx, p[i]); }
    float s = 0.f;
    #pragma unroll
    for (int i = 0; i < 6; i++) { p[i] = __expf(p[i] - mx); s += p[i]; }
    float inv = 1.f / s;
    #pragma unroll
    for (int i = 0; i < 6; i++) p[i] *= inv;
    float mk[4] = { p[0] + p[1] + p[2], p[0] + p[3] + p[4],
                    p[1] + p[3] + p[5], p[2] + p[4] + p[5] };
    int K = G * 4;
    const float* wr = w + (long long)o * K + g * 4;
    ushort_t* wo = wm + (idx / G) * (long long)K + g * 4;
    #pragma unroll
    for (int k = 0; k < 4; k++) wo[k] = f2b(wr[k] * mk[k]);
}

__device__ __forceinline__ void canon_item(const float* __restrict__ src,
                                           ushort_t* __restrict__ dst,
                                           long long i) {
    long long base = i * 8;
    us8 o;
    #pragma unroll
    for (int k = 0; k < 8; k++) o[k] = f2b(src[base + k]);
    *(us8*)(dst + base) = o;
}

// section block counts
#define PB0 256    // maskw fc1  (65536 items)
#define PB1 2048   // maskw fc2  (524288)
#define PB2 2048   // maskw fc3  (524288)
#define PB3 64     // maskw fc4  (16384)
#define PB4 256    // canon inputs (65536 x8)
#define PB5 2048   // canon hidden (524288 x8)
#define PB6 384    // canon wih (98304 x8)
#define PB7 384    // canon whh (98304 x8)
#define PREP_BLOCKS (PB0+PB1+PB2+PB3+PB4+PB5+PB6+PB7)

__global__ void prep_kernel(const float* fc1_al, const float* fc1_w, ushort_t* wm1,
                            const float* fc2_al, const float* fc2_w, ushort_t* wm2,
                            const float* fc3_al, const float* fc3_w, ushort_t* wm3,
                            const float* fc4_al, const float* fc4_w, ushort_t* wm4,
                            const float* inputs, ushort_t* inp_b,
                            const float* hidden, ushort_t* hid_b,
                            const float* wih, ushort_t* wihb,
                            const float* whh, ushort_t* whhb) {
    int b = blockIdx.x;
    int tid = threadIdx.x;
    if (b < PB0) { maskw_item(fc1_al, fc1_w, wm1, (long long)b * 256 + tid, 512, 16); return; }
    b -= PB0;
    if (b < PB1) { maskw_item(fc2_al, fc2_w, wm2, (long long)b * 256 + tid, 512, 128); return; }
    b -= PB1;
    if (b < PB2) { maskw_item(fc3_al, fc3_w, wm3, (long long)b * 256 + tid, 512, 128); return; }
    b -= PB2;
    if (b < PB3) { maskw_item(fc4_al, fc4_w, wm4, (long long)b * 256 + tid, 16, 128); return; }
    b -= PB3;
    if (b < PB4) { canon_item(inputs, inp_b, (long long)b * 256 + tid); return; }
    b -= PB4;
    if (b < PB5) { canon_item(hidden, hid_b, (long long)b * 256 + tid); return; }
    b -= PB5;
    if (b < PB6) { canon_item(wih, wihb, (long long)b * 256 + tid); return; }
    b -= PB6;
    canon_item(whh, whhb, (long long)b * 256 + tid);
}

// ---------------------------------------------------------------------------
// LDS layout: 64x32 bf16 tile, fragment-linear with XOR swizzle.
//   element (row, k=grp*8+e) -> ushort idx ((row*4 + (grp ^ ((row>>2)&3)))*8 + e)
// Staging writes (srow=tid>>2, grp=tid&3) and MFMA fragment reads
// (row=base+l16, grp=quad) are both bank-balanced at every wave-phase
// granularity (paper-verified vs the LDT=40 layout's measured 8.4M conflicts).
// ---------------------------------------------------------------------------
#define BM 64
#define BN 64
#define BK 32

template <typename OT>
__launch_bounds__(256, 4)
__global__ void gemm_tiled(const ushort_t* __restrict__ In, int ldin,
                           const ushort_t* __restrict__ W, long long wstride,
                           const float* __restrict__ bias,
                           OT* __restrict__ Out, int ldo,
                           const int4* __restrict__ ttab,
                           const int* __restrict__ tcount,
                           const int* __restrict__ gather,
                           const int* __restrict__ scatter,
                           int O, int K, int relu) {
    int t = blockIdx.x;
    if (t >= *tcount) return;
    int4 tt = ttab[t];
    int a = tt.x, pos0 = tt.y, pos1 = tt.z;
    int o0 = blockIdx.y * BN;

    __shared__ ushort_t As[2048];
    __shared__ ushort_t Bs[2048];

    int tid = threadIdx.x;
    int wave = tid >> 6, lane = tid & 63;
    int wr = (wave >> 1) & 1, wc = wave & 1;
    int quad = lane >> 4, l16 = lane & 15;
    int srow = tid >> 2, sgrp = tid & 3;
    int scol = sgrp * 8;
    int wsoff = (srow * 4 + (sgrp ^ ((srow >> 2) & 3))) * 8;
    int rl = (l16 * 4 + (quad ^ ((l16 >> 2) & 3))) * 8;

    int apos = pos0 + srow;
    int apos_c = apos < pos1 ? apos : (pos1 - 1);
    int arow = (gather ? gather[apos_c] : apos_c) & 8191;
    const ushort_t* aptr = In + (long long)arow * ldin + scol;

    int brow = o0 + srow;
    int brow_c = brow < O ? brow : (O - 1);
    const ushort_t* bptr = W + (long long)a * wstride + (long long)brow_c * K + scol;

    f32x4 acc[2][2];
    #pragma unroll
    for (int i = 0; i < 2; i++)
        #pragma unroll
        for (int j = 0; j < 2; j++) acc[i][j] = (f32x4){0.f, 0.f, 0.f, 0.f};

    for (int k0 = 0; k0 < K; k0 += BK) {
        us8 av = *(const us8*)(aptr + k0);
        us8 bv = *(const us8*)(bptr + k0);
        __syncthreads();
        *(us8*)(&As[wsoff]) = av;
        *(us8*)(&Bs[wsoff]) = bv;
        __syncthreads();

        bf16x8 af[2], bfr[2];
        #pragma unroll
        for (int u = 0; u < 2; u++) {
            af[u]  = *(const bf16x8*)(&As[(wr * 2 + u) * 512 + rl]);
            bfr[u] = *(const bf16x8*)(&Bs[(wc * 2 + u) * 512 + rl]);
        }
        #pragma unroll
        for (int i = 0; i < 2; i++)
            #pragma unroll
            for (int j = 0; j < 2; j++)
                acc[i][j] = __builtin_amdgcn_mfma_f32_16x16x32_bf16(af[i], bfr[j], acc[i][j], 0, 0, 0);
    }

    #pragma unroll
    for (int i = 0; i < 2; i++) {
        int mbase = wr * 32 + i * 16 + quad * 4;
        #pragma unroll
        for (int j = 0; j < 2; j++) {
            int col = o0 + wc * 32 + j * 16 + l16;
            if (col < O) {
                float bias_v = bias ? bias[col] : 0.f;
                #pragma unroll
                for (int r = 0; r < 4; r++) {
                    int pos = pos0 + mbase + r;
                    if (pos < pos1) {
                        float v = acc[i][j][r] + bias_v;
                        if (relu) v = fmaxf(v, 0.f);
                        int orow = (scatter ? scatter[pos] : pos) & 8191;
                        store_o(&Out[(long long)orow * ldo + col], v);
                    }
                }
            }
        }
    }
}

// ---------------------------------------------------------------------------
// Fused GRU (6 accumulator groups), swizzled LDS (32 KB/block).
// ---------------------------------------------------------------------------
__launch_bounds__(256, 2)
__global__ void gru_fused(const ushort_t* __restrict__ y1,       // [N,H] pos order bf16
                          const ushort_t* __restrict__ hid_b,    // [N,H] orig order bf16
                          const float* __restrict__ hidden_f,    // [N,H] orig order fp32
                          const ushort_t* __restrict__ wihb,     // [3H,H] bf16
                          const ushort_t* __restrict__ whhb,     // [3H,H] bf16
                          const float* __restrict__ bih,
                          const float* __restrict__ bhh,
                          const int* __restrict__ perm,
                          float* __restrict__ out_h_f,           // [N,H] orig order fp32
                          ushort_t* __restrict__ hp,             // [N,H] pos order bf16
                          int N, int H) {
    int m0 = blockIdx.x * 64;
    int c0 = blockIdx.y * 64;

    __shared__ ushort_t Ay[2048];
    __shared__ ushort_t Ah[2048];
    __shared__ ushort_t Bt[6][2048];

    int tid = threadIdx.x;
    int wave = tid >> 6, lane = tid & 63;
    int wr = (wave >> 1) & 1, wc = wave & 1;
    int quad = lane >> 4, l16 = lane & 15;
    int srow = tid >> 2, sgrp = tid & 3;
    int scol = sgrp * 8;
    int wsoff = (srow * 4 + (sgrp ^ ((srow >> 2) & 3))) * 8;
    int rl = (l16 * 4 + (quad ^ ((l16 >> 2) & 3))) * 8;

    int hrow = perm[m0 + srow] & 8191;
    const ushort_t* ay_p = y1 + (long long)(m0 + srow) * H + scol;
    const ushort_t* ah_p = hid_b + (long long)hrow * H + scol;
    const ushort_t* bp[6];
    #pragma unroll
    for (int g = 0; g < 3; g++)
        bp[g] = wihb + (long long)(g * H + c0 + srow) * H + scol;
    #pragma unroll
    for (int g = 3; g < 6; g++)
        bp[g] = whhb + (long long)((g - 3) * H + c0 + srow) * H + scol;

    f32x4 acc[6][2][2];
    #pragma unroll
    for (int g = 0; g < 6; g++)
        #pragma unroll
        for (int i = 0; i < 2; i++)
            #pragma unroll
            for (int j = 0; j < 2; j++) acc[g][i][j] = (f32x4){0.f, 0.f, 0.f, 0.f};

    for (int k0 = 0; k0 < H; k0 += BK) {
        us8 va = *(const us8*)(ay_p + k0);
        us8 vh = *(const us8*)(ah_p + k0);
        us8 vb[6];
        #pragma unroll
        for (int g = 0; g < 6; g++) vb[g] = *(const us8*)(bp[g] + k0);
        __syncthreads();
        *(us8*)(&Ay[wsoff]) = va;
        *(us8*)(&Ah[wsoff]) = vh;
        #pragma unroll
        for (int g = 0; g < 6; g++) *(us8*)(&Bt[g][wsoff]) = vb[g];
        __syncthreads();

        bf16x8 ayf[2], ahf[2];
        #pragma unroll
        for (int u = 0; u < 2; u++) {
            ayf[u] = *(const bf16x8*)(&Ay[(wr * 2 + u) * 512 + rl]);
            ahf[u] = *(const bf16x8*)(&Ah[(wr * 2 + u) * 512 + rl]);
        }
        #pragma unroll
        for (int g = 0; g < 6; g++) {
            bf16x8 bfr[2];
            #pragma unroll
            for (int u = 0; u < 2; u++)
                bfr[u] = *(const bf16x8*)(&Bt[g][(wc * 2 + u) * 512 + rl]);
            #pragma unroll
            for (int i = 0; i < 2; i++)
                #pragma unroll
                for (int j = 0; j < 2; j++)
                    acc[g][i][j] = __builtin_amdgcn_mfma_f32_16x16x32_bf16(
                        (g < 3) ? ayf[i] : ahf[i], bfr[j], acc[g][i][j], 0, 0, 0);
        }
    }

    #pragma unroll
    for (int i = 0; i < 2; i++) {
        #pragma unroll
        for (int r = 0; r < 4; r++) {
            int pos = m0 + wr * 32 + i * 16 + quad * 4 + r;
            int norig = perm[pos] & 8191;
            #pragma unroll
            for (int j = 0; j < 2; j++) {
                int col = c0 + wc * 32 + j * 16 + l16;
                float ir = acc[0][i][j][r] + bih[col];
                float iz = acc[1][i][j][r] + bih[H + col];
                float in_ = acc[2][i][j][r] + bih[2 * H + col];
                float hr = acc[3][i][j][r] + bhh[col];
                float hz = acc[4][i][j][r] + bhh[H + col];
                float hn = acc[5][i][j][r] + bhh[2 * H + col];
                float rg = sigmoidf_(ir + hr);
                float zg = sigmoidf_(iz + hz);
                float ng = tanhf(in_ + rg * hn);
                float hv = hidden_f[(long long)norig * H + col];
                float hnew = (1.f - zg) * ng + zg * hv;
                out_h_f[(long long)norig * H + col] = hnew;
                hp[(long long)pos * H + col] = f2b(hnew);
            }
        }
    }
}

// ---------------------------------------------------------------------------
extern "C" void kernel_launch(void* const* d_in, const int* in_sizes, int n_in,
                              void* d_out, int out_size, void* d_ws, size_t ws_size,
                              hipStream_t stream) {
    (void)in_sizes; (void)n_in;
    const int N = 8192, A = 8, E = 64, H = 512, NA = 16;

    float* out_f = (float*)d_out;
    float* out_q = out_f;                        // [N, NA] fp32
    float* out_h = out_f + (size_t)N * NA;       // [N, H] fp32, original row order

    char* p = (char*)d_ws;
    auto alloc = [&](size_t b) { char* r = p; p += (b + 255) & ~(size_t)255; return r; };
    int*  perm   = (int*)alloc((size_t)N * 4);
    int*  seg    = (int*)alloc(16 * 4);
    int4* ttab   = (int4*)alloc(144 * 16);
    int*  tcount = (int*)alloc(256);
    ushort_t* wm1   = (ushort_t*)alloc((size_t)A * H * E * 2);
    ushort_t* wm2   = (ushort_t*)alloc((size_t)A * H * H * 2);
    ushort_t* wm3   = (ushort_t*)alloc((size_t)A * H * H * 2);
    ushort_t* wm4   = (ushort_t*)alloc((size_t)A * NA * H * 2);
    ushort_t* y1    = (ushort_t*)alloc((size_t)N * H * 2);
    ushort_t* inp_b = (ushort_t*)alloc((size_t)N * E * 2);
    ushort_t* hid_b = (ushort_t*)alloc((size_t)N * H * 2);
    ushort_t* wihb  = (ushort_t*)alloc((size_t)3 * H * H * 2);
    ushort_t* whhb  = (ushort_t*)alloc((size_t)3 * H * H * 2);
    ushort_t* hp    = (ushort_t*)alloc((size_t)N * H * 2);
    size_t need = (size_t)(p - (char*)d_ws);
    ushort_t* q2 = y1;     // alias: y1 dead after gru_fused
    ushort_t* q3 = hid_b;  // alias: hid_b dead after gru_fused

    if (ws_size < need) {
        fill_kernel<<<(unsigned)((out_size + 255) / 256), 256, 0, stream>>>(
            out_f, out_size, 1000.f);
        return;
    }

    const float* inputs = (const float*)d_in[0];
    const float* hidden = (const float*)d_in[1];
    const int*   ids    = (const int*)d_in[2];
    const float* fc1_w  = (const float*)d_in[3];
    const float* fc1_b  = (const float*)d_in[4];
    const float* fc1_al = (const float*)d_in[5];
    const float* wih    = (const float*)d_in[6];
    const float* whh    = (const float*)d_in[7];
    const float* bih    = (const float*)d_in[8];
    const float* bhh    = (const float*)d_in[9];
    const float* fc2_w  = (const float*)d_in[10];
    const float* fc2_b  = (const float*)d_in[11];
    const float* fc2_al = (const float*)d_in[12];
    const float* fc3_w  = (const float*)d_in[13];
    const float* fc3_b  = (const float*)d_in[14];
    const float* fc3_al = (const float*)d_in[15];
    const float* fc4_w  = (const float*)d_in[16];
    const float* fc4_b  = (const float*)d_in[17];
    const float* fc4_al = (const float*)d_in[18];

    sort_kernel<<<1, 1024, 0, stream>>>(ids, N, perm, seg, ttab, tcount);

    prep_kernel<<<PREP_BLOCKS, 256, 0, stream>>>(
        fc1_al, fc1_w, wm1, fc2_al, fc2_w, wm2, fc3_al, fc3_w, wm3,
        fc4_al, fc4_w, wm4, inputs, inp_b, hidden, hid_b, wih, wihb, whh, whhb);

    dim3 blk(256);
    // fc1: gather inputs via perm, relu -> y1 (pos order, bf16)
    gemm_tiled<ushort_t><<<dim3(136, H / BN), blk, 0, stream>>>(
        inp_b, E, wm1, (long long)H * E, fc1_b, y1, H, ttab, tcount,
        perm, nullptr, H, E, 1);
    // fused GRU -> h' fp32 to d_out (orig order) + bf16 hp (pos order)
    gru_fused<<<dim3(N / 64, H / 64), blk, 0, stream>>>(
        y1, hid_b, hidden, wihb, whhb, bih, bhh, perm, out_h, hp, N, H);
    // fc2: pos-order input, relu -> q2
    gemm_tiled<ushort_t><<<dim3(136, H / BN), blk, 0, stream>>>(
        hp, H, wm2, (long long)H * H, fc2_b, q2, H, ttab, tcount,
        nullptr, nullptr, H, H, 1);
    // fc3: relu -> q3
    gemm_tiled<ushort_t><<<dim3(136, H / BN), blk, 0, stream>>>(
        q2, H, wm3, (long long)H * H, fc3_b, q3, H, ttab, tcount,
        nullptr, nullptr, H, H, 1);
    // fc4: scatter q fp32 to d_out (orig order)
    gemm_tiled<float><<<dim3(136, 1), blk, 0, stream>>>(
        q3, H, wm4, (long long)NA * H, fc4_b, out_q, NA, ttab, tcount,
        nullptr, perm, NA, H, 0);
}